// Round 15
// baseline (149.201 us; speedup 1.0000x reference)
//
#include <hip/hip_runtime.h>
#include <math.h>

#define B_   8
#define S_   512
#define DM_  768
#define H_   12
#define D_   64
#define BH_  96
#define M_   4096   // B_*S_

typedef _Float16 f16x8 __attribute__((ext_vector_type(8)));
typedef _Float16 f16x4 __attribute__((ext_vector_type(4)));
typedef float    f32x4 __attribute__((ext_vector_type(4)));

__device__ __forceinline__ float dual_spike(float x) {
    return x >= 1.0f ? 1.0f : (x <= -1.0f ? -1.0f : 0.0f);
}

__device__ __forceinline__ void gload_lds16(const void* g, void* l) {
    __builtin_amdgcn_global_load_lds(
        (const __attribute__((address_space(1))) unsigned int*)g,
        (__attribute__((address_space(3))) unsigned int*)l, 16, 0, 0);
}

// Shared QK dot chain — MUST be bitwise identical wherever t is derived.
__device__ __forceinline__ f32x4 qk_dot(const f16x8* qa, const f16x8* kh, const f16x8* kl) {
    f32x4 acc = (f32x4){0.f, 0.f, 0.f, 0.f};
    acc = __builtin_amdgcn_mfma_f32_16x16x32_f16(qa[0], kh[0], acc, 0, 0, 0);
    acc = __builtin_amdgcn_mfma_f32_16x16x32_f16(qa[0], kl[0], acc, 0, 0, 0);
    acc = __builtin_amdgcn_mfma_f32_16x16x32_f16(qa[1], kh[1], acc, 0, 0, 0);
    acc = __builtin_amdgcn_mfma_f32_16x16x32_f16(qa[1], kl[1], acc, 0, 0, 0);
    return acc;
}

// ---------------- Prepass: X -> fp16 hi/lo planes, FLAT [kc 24][fm 256][512] ----
__global__ __launch_bounds__(256) void prep_x(
    const float* __restrict__ X, _Float16* __restrict__ Xh, _Float16* __restrict__ Xl)
{
    int wid  = blockIdx.x * 4 + (threadIdx.x >> 6);   // 0..6143
    int lane = threadIdx.x & 63;
    int fm = wid & 255, kc = wid >> 8;
    int row = fm * 16 + (lane & 15);
    int col = kc * 32 + (lane >> 4) * 8;
    const float4* p = reinterpret_cast<const float4*>(&X[row * DM_ + col]);
    float4 x0 = p[0], x1 = p[1];
    float xs[8] = {x0.x, x0.y, x0.z, x0.w, x1.x, x1.y, x1.z, x1.w};
    f16x8 hi, lo;
    #pragma unroll
    for (int j = 0; j < 8; ++j) {
        float v = xs[j] * 256.0f;
        _Float16 h = (_Float16)v;
        hi[j] = h;
        lo[j] = (_Float16)(v - (float)h);
    }
    size_t out = ((size_t)wid * 64 + lane) * 8;
    *reinterpret_cast<f16x8*>(&Xh[out]) = hi;
    *reinterpret_cast<f16x8*>(&Xl[out]) = lo;
}

// ---------------- Prepass: W -> transposed FLAT [which 3][kc 24][fn 48][512] ----
__global__ __launch_bounds__(256) void prep_w(
    const float* __restrict__ Wq, const float* __restrict__ Wk, const float* __restrict__ Wv,
    _Float16* __restrict__ Wth, _Float16* __restrict__ Wtl)
{
    int wid  = blockIdx.x * 4 + (threadIdx.x >> 6);   // 0..3455
    int lane = threadIdx.x & 63;
    int fn = wid % 48, kc = (wid / 48) % 24, which = wid / 1152;
    const float* __restrict__ W = which == 0 ? Wq : (which == 1 ? Wk : Wv);
    int c = lane & 15, g = lane >> 4;
    int ncol = fn * 16 + c;
    int krow = kc * 32 + g * 8;
    f16x8 hi, lo;
    #pragma unroll
    for (int j = 0; j < 8; ++j) {
        float v = W[(krow + j) * DM_ + ncol] * 256.0f;
        _Float16 h = (_Float16)v;
        hi[j] = h;
        lo[j] = (_Float16)(v - (float)h);
    }
    size_t out = ((size_t)wid * 64 + lane) * 8;
    *reinterpret_cast<f16x8*>(&Wth[out]) = hi;
    *reinterpret_cast<f16x8*>(&Wtl[out]) = lo;
}

// ---------------- Kernel 1: QKV via fp16 split MFMA --------------------------
// v13 = R14 (fused fragment epilogue) + T4 counted-vmcnt pipeline:
// raw s_barrier + s_waitcnt vmcnt(4), prefetch distance 2 — loads stay in
// flight ACROSS barriers (HK protocol; __syncthreads would drain vmcnt(0)).
// Each wave issues exactly 4 gload_lds per stage (wave 7: 0), so vmcnt(4)
// proves the PREVIOUS stage's loads landed; the barrier publishes block-wide.
__global__ __launch_bounds__(512, 4) void qkv_mfma(
    const _Float16* __restrict__ Xh, const _Float16* __restrict__ Xl,
    const _Float16* __restrict__ Wth, const _Float16* __restrict__ Wtl,
    const float* __restrict__ X,
    const float* __restrict__ Wq, const float* __restrict__ bq,
    const float* __restrict__ Wk, const float* __restrict__ bk,
    const float* __restrict__ Wv, const float* __restrict__ bv,
    _Float16* __restrict__ Qf, _Float16* __restrict__ Kfh, _Float16* __restrict__ Kfl,
    _Float16* __restrict__ Vfh, _Float16* __restrict__ Vfl)
{
    // XCD epochs: per XCD 3 epochs x (4 mb x 8 nb) of one which.
    const int orig = blockIdx.x;
    const int xcd = orig & 7, idx = orig >> 3;        // idx 0..95
    const int epoch = idx >> 5, sub = idx & 31;       // 3 epochs x 32 blocks
    const int mw = xcd * 12 + epoch * 4 + (sub >> 3); // 0..95 bijective
    const int which = mw / 32, mb = mw % 32;
    const int nb = sub & 7;                           // 0..7 (96-col panels)

    const float* __restrict__ bias = which == 0 ? bq : (which == 1 ? bk : bv);

    // [buf][Ah 4096 | Al 4096 | Bh 3072 | Bl 3072] halves = 28KB/buf
    __shared__ __align__(16) _Float16 lds[2][14336];

    const int tid = threadIdx.x;
    const int wave = tid >> 6, lane = tid & 63;
    const int wm = wave >> 1, wn = wave & 1;          // wm 0..3, wn 0..1
    const int l15 = lane & 15, g = lane >> 4;

    auto stage = [&](int kc, int bsel) {
        #pragma unroll
        for (int c = 0; c < 4; ++c) {
            int u = wave * 4 + c;                     // 0..31; units 0..27 valid
            if (u < 28) {
                const _Float16* src;
                if (u < 8)       src = Xh  + (size_t)(kc * 256 + mb * 8 + u) * 512;
                else if (u < 16) src = Xl  + (size_t)(kc * 256 + mb * 8 + (u - 8)) * 512;
                else if (u < 22) src = Wth + (size_t)((which * 24 + kc) * 48 + nb * 6 + (u - 16)) * 512;
                else             src = Wtl + (size_t)((which * 24 + kc) * 48 + nb * 6 + (u - 22)) * 512;
                gload_lds16(src + lane * 8, &lds[bsel][u * 512]);
            }
        }
    };

    f32x4 acc[2][3];
    #pragma unroll
    for (int i = 0; i < 2; ++i)
        #pragma unroll
        for (int j = 0; j < 3; ++j) acc[i][j] = (f32x4){0.f, 0.f, 0.f, 0.f};

    // prologue: stage 0 and 1; wait stage-0 (4 newest = stage-1 may stay out)
    stage(0, 0);
    stage(1, 1);
    asm volatile("s_waitcnt vmcnt(4)" ::: "memory");
    __builtin_amdgcn_sched_barrier(0);
    __builtin_amdgcn_s_barrier();
    int cur = 0;

    for (int kc = 0; kc < 24; ++kc) {
        const _Float16* Bf = lds[cur];
        f16x8 ah[2], al[2], bh[3], bl[3];
        #pragma unroll
        for (int f = 0; f < 2; ++f) {
            ah[f] = *reinterpret_cast<const f16x8*>(&Bf[(wm * 2 + f) * 512 + lane * 8]);
            al[f] = *reinterpret_cast<const f16x8*>(&Bf[4096 + (wm * 2 + f) * 512 + lane * 8]);
        }
        #pragma unroll
        for (int fb = 0; fb < 3; ++fb) {
            bh[fb] = *reinterpret_cast<const f16x8*>(&Bf[8192 + (wn * 3 + fb) * 512 + lane * 8]);
            bl[fb] = *reinterpret_cast<const f16x8*>(&Bf[11264 + (wn * 3 + fb) * 512 + lane * 8]);
        }
        __builtin_amdgcn_s_setprio(1);
        #pragma unroll
        for (int i = 0; i < 2; ++i)
            #pragma unroll
            for (int j = 0; j < 3; ++j) {
                acc[i][j] = __builtin_amdgcn_mfma_f32_16x16x32_f16(ah[i], bh[j], acc[i][j], 0, 0, 0);
                acc[i][j] = __builtin_amdgcn_mfma_f32_16x16x32_f16(ah[i], bl[j], acc[i][j], 0, 0, 0);
                acc[i][j] = __builtin_amdgcn_mfma_f32_16x16x32_f16(al[i], bh[j], acc[i][j], 0, 0, 0);
            }
        __builtin_amdgcn_s_setprio(0);
        __builtin_amdgcn_sched_barrier(0);
        __builtin_amdgcn_s_barrier();          // all waves done READING lds[cur]
        if (kc + 2 < 24) {
            stage(kc + 2, cur);                // overwrite cur with kc+2 (in flight)
            asm volatile("s_waitcnt vmcnt(4)" ::: "memory");   // kc+1 landed (mine)
        } else {
            asm volatile("s_waitcnt vmcnt(0)" ::: "memory");   // tail: drain all
        }
        __builtin_amdgcn_sched_barrier(0);
        __builtin_amdgcn_s_barrier();          // kc+1 landed (all waves)
        cur ^= 1;
    }

    const float* __restrict__ Worig = which == 0 ? Wq : (which == 1 ? Wk : Wv);

    #pragma unroll
    for (int i = 0; i < 2; ++i) {
        #pragma unroll
        for (int j = 0; j < 3; ++j) {
            int n = nb * 96 + wn * 48 + j * 16 + l15;
            int h = n >> 6, d = n & 63;
            float bn = bias[n];
            float vals[4];
            #pragma unroll
            for (int r = 0; r < 4; ++r) {
                float val = acc[i][j][r] * (1.0f / 65536.0f) + bn;
                if (which < 2) {
                    bool need = fabsf(fabsf(val) - 1.0f) < 1e-4f;
                    unsigned long long msk = __ballot(need);
                    // wave-parallel deterministic recompute per flagged lane
                    while (msk) {
                        int L = (int)__builtin_ctzll(msk);
                        msk &= msk - 1;
                        int Lm = mb * 128 + wm * 32 + i * 16 + (L >> 4) * 4 + r;
                        int Ln = nb * 96 + wn * 48 + j * 16 + (L & 15);
                        const float* xr = X + (size_t)Lm * DM_;
                        const float* wc = Worig + Ln;
                        float xs[12], wsv[12];
                        #pragma unroll
                        for (int t = 0; t < 12; ++t) {
                            int e = t * 64 + lane;
                            xs[t]  = xr[e];
                            wsv[t] = wc[(size_t)e * DM_];
                        }
                        float part = 0.0f;
                        #pragma unroll
                        for (int t = 0; t < 12; ++t) part = fmaf(xs[t], wsv[t], part);
                        part += __shfl_xor(part, 1);
                        part += __shfl_xor(part, 2);
                        part += __shfl_xor(part, 4);
                        part += __shfl_xor(part, 8);
                        part += __shfl_xor(part, 16);
                        part += __shfl_xor(part, 32);
                        if (lane == L) val = part + bn;
                    }
                }
                vals[r] = val;
            }
            int m0 = mb * 128 + wm * 32 + i * 16 + g * 4;   // s for r=0
            int b = m0 >> 9, s0 = m0 & 511;
            int bh_ = b * H_ + h;
            if (which == 0) {
                #pragma unroll
                for (int r = 0; r < 4; ++r) {
                    int s = s0 + r;
                    size_t unit = (size_t)(bh_ * 32 + (s >> 4)) * 2 + (d >> 5);
                    size_t off = unit * 512 + (size_t)(((d >> 3) & 3) * 16 + (s & 15)) * 8 + (d & 7);
                    Qf[off] = (_Float16)dual_spike(vals[r]);
                }
            } else if (which == 1) {
                #pragma unroll
                for (int r = 0; r < 4; ++r) {
                    int s = s0 + r;
                    float kv = 0.5f * dual_spike(vals[r]) + 0.5f * vals[r];
                    float sv = kv * 256.0f;
                    _Float16 hh = (_Float16)sv;
                    size_t unit = (size_t)(bh_ * 32 + (s >> 4)) * 2 + (d >> 5);
                    size_t off = unit * 512 + (size_t)(((d >> 3) & 3) * 16 + (s & 15)) * 8 + (d & 7);
                    Kfh[off] = hh;
                    Kfl[off] = (_Float16)(sv - (float)hh);
                }
            } else {
                f16x4 ph4, pl4;
                #pragma unroll
                for (int r = 0; r < 4; ++r) {
                    _Float16 hh = (_Float16)vals[r];
                    ph4[r] = hh;
                    pl4[r] = (_Float16)(vals[r] - (float)hh);
                }
                size_t unit = (size_t)(bh_ * 16 + (s0 >> 5)) * 4 + (d >> 4);
                size_t off = unit * 512 + (size_t)(((s0 >> 3) & 3) * 16 + (d & 15)) * 8 + (s0 & 7);
                *reinterpret_cast<f16x4*>(&Vfh[off]) = ph4;
                *reinterpret_cast<f16x4*>(&Vfl[off]) = pl4;
            }
        }
    }
}

// ---------------- Kernel 2: score threshold counts via MFMA --------------------
__global__ __launch_bounds__(256) void score_sums(
    const _Float16* __restrict__ Qf, const _Float16* __restrict__ Kfh,
    const _Float16* __restrict__ Kfl,
    float* __restrict__ xh, float* __restrict__ xw)
{
    const int orig = blockIdx.x;
    const int xcd = orig & 7, idx = orig >> 3;
    const int bh = xcd * 12 + idx / 8, qt = idx & 7;
    const int tid = threadIdx.x, wave = tid >> 6, lane = tid & 63;
    const int l15 = lane & 15, g = lane >> 4;

    __shared__ float rowred[4][64];

    f16x8 qa[4][2];
    #pragma unroll
    for (int sf = 0; sf < 4; ++sf) {
        const _Float16* qb = Qf + (size_t)((bh * 32 + qt * 4 + sf) * 2) * 512 + lane * 8;
        qa[sf][0] = *reinterpret_cast<const f16x8*>(qb);
        qa[sf][1] = *reinterpret_cast<const f16x8*>(qb + 512);
    }
    float rowc[4][4];
    #pragma unroll
    for (int sf = 0; sf < 4; ++sf)
        #pragma unroll
        for (int r = 0; r < 4; ++r) rowc[sf][r] = 0.0f;

    for (int sc8 = 0; sc8 < 8; ++sc8) {
        int scol16 = sc8 * 4 + wave;
        const _Float16* kbh = Kfh + (size_t)((bh * 32 + scol16) * 2) * 512 + lane * 8;
        const _Float16* kbl = Kfl + (size_t)((bh * 32 + scol16) * 2) * 512 + lane * 8;
        f16x8 kh[2] = {*reinterpret_cast<const f16x8*>(kbh),
                       *reinterpret_cast<const f16x8*>(kbh + 512)};
        f16x8 kl[2] = {*reinterpret_cast<const f16x8*>(kbl),
                       *reinterpret_cast<const f16x8*>(kbl + 512)};
        float csum = 0.0f;
        #pragma unroll
        for (int sf = 0; sf < 4; ++sf) {
            f32x4 acc = qk_dot(qa[sf], kh, kl);
            #pragma unroll
            for (int r = 0; r < 4; ++r) {
                float t1 = acc[r] >= 2048.0f ? 1.0f : 0.0f;   // dot >= 8
                rowc[sf][r] += t1;
                csum += t1;
            }
        }
        csum += __shfl_xor(csum, 16);
        csum += __shfl_xor(csum, 32);
        if (g == 0) atomicAdd(&xw[bh * S_ + scol16 * 16 + l15], csum);
    }
    #pragma unroll
    for (int sf = 0; sf < 4; ++sf)
        #pragma unroll
        for (int r = 0; r < 4; ++r) {
            float sv = rowc[sf][r];
            sv += __shfl_xor(sv, 1); sv += __shfl_xor(sv, 2);
            sv += __shfl_xor(sv, 4); sv += __shfl_xor(sv, 8);
            if (l15 == 0) rowred[wave][sf * 16 + g * 4 + r] = sv;
        }
    __syncthreads();
    if (tid < 64) {
        float sv = rowred[0][tid] + rowred[1][tid] + rowred[2][tid] + rowred[3][tid];
        xh[bh * S_ + qt * 64 + tid] = sv;    // exact count, no atomics needed
    }
}

// ---------------- Kernel 3a: conv1 y + per-block partial stats (deterministic) --
__global__ __launch_bounds__(256) void small_a(
    const float* __restrict__ xh, const float* __restrict__ xw,
    const float* __restrict__ c1w,
    float* __restrict__ y, float* __restrict__ stats_part)   // [24][2]
{
    const int tid = threadIdx.x;
    const int br = blockIdx.x;           // b*3 + r
    const int r = br % 3, b = br / 3;
    __shared__ float c1s[12];
    __shared__ float red[256], red2[256];
    if (tid < 12) c1s[tid] = c1w[r * 12 + tid];
    __syncthreads();

    float psum = 0.0f, psq = 0.0f;
    for (int n = tid; n < 1024; n += 256) {
        float acc = 0.0f;
        #pragma unroll
        for (int h = 0; h < 12; ++h) {
            float cv = (n < 512) ? xh[(b * H_ + h) * S_ + n]
                                 : xw[(b * H_ + h) * S_ + (n - 512)];
            acc = fmaf(c1s[h], cv * (1.0f / 512.0f), acc);
        }
        y[br * 1024 + n] = acc;
        psum += acc;
        psq = fmaf(acc, acc, psq);
    }
    red[tid] = psum; red2[tid] = psq;
    __syncthreads();
    for (int o = 128; o > 0; o >>= 1) {
        if (tid < o) { red[tid] += red[tid + o]; red2[tid] += red2[tid + o]; }
        __syncthreads();
    }
    if (tid == 0) {
        stats_part[br * 2 + 0] = red[0];
        stats_part[br * 2 + 1] = red2[0];
    }
}

// ---------------- Kernel 3b: BN + relu + conv + sigmoid ------------------------
__global__ __launch_bounds__(512) void small_b(
    const float* __restrict__ y, const float* __restrict__ stats_part,
    const float* __restrict__ gamma, const float* __restrict__ beta,
    const float* __restrict__ chw, const float* __restrict__ cww,
    float* __restrict__ s_h, float* __restrict__ s_w)
{
    int e = blockIdx.x * 512 + threadIdx.x;   // 0..49151
    int s = e & 511; int bh = e >> 9; int h = bh % H_; int b = bh / H_;
    float ah = 0.0f, aw = 0.0f;
    #pragma unroll
    for (int r = 0; r < 3; ++r) {
        float su = 0.0f, sq = 0.0f;
        #pragma unroll
        for (int bb = 0; bb < 8; ++bb) {     // fixed order -> deterministic
            su += stats_part[(bb * 3 + r) * 2 + 0];
            sq += stats_part[(bb * 3 + r) * 2 + 1];
        }
        float mu = su * (1.0f / 8192.0f);
        float var = sq * (1.0f / 8192.0f) - mu * mu;
        float rs = rsqrtf(var + 1e-5f);
        int yb = (b * 3 + r) << 10;
        float yh = fmaxf((y[yb + s]       - mu) * rs * gamma[r] + beta[r], 0.0f);
        float yw = fmaxf((y[yb + 512 + s] - mu) * rs * gamma[r] + beta[r], 0.0f);
        ah = fmaf(chw[h * 3 + r], yh, ah);
        aw = fmaf(cww[h * 3 + r], yw, aw);
    }
    s_h[e] = 1.0f / (1.0f + expf(-ah));
    s_w[e] = 1.0f / (1.0f + expf(-aw));
}

// ---------------- Kernel 4: full-MFMA attention (R13, unchanged) ----------------
__global__ __launch_bounds__(256) void attn_pv(
    const _Float16* __restrict__ Qf, const _Float16* __restrict__ Kfh,
    const _Float16* __restrict__ Kfl,
    const _Float16* __restrict__ Vfh, const _Float16* __restrict__ Vfl,
    const float* __restrict__ mask, const float* __restrict__ s_h,
    const float* __restrict__ s_w, float* __restrict__ out)
{
    __shared__ __align__(16) _Float16 Kst[2][4096];
    __shared__ __align__(16) _Float16 Vst[2][4096];
    __shared__ __align__(16) float P_lds[64][68];

    const int orig = blockIdx.x;
    const int xcd = orig & 7, idx = orig >> 3;
    const int bh = xcd * 12 + idx / 8, qt = idx & 7;
    const int b = bh / H_, h = bh % H_;
    const int q0 = qt * 64;
    const int tid = threadIdx.x, wave = tid >> 6, lane = tid & 63;
    const int l15 = lane & 15, g = lane >> 4;
    const int rl = wave * 16 + g * 4;

    const _Float16* qb = Qf + (size_t)((bh * 32 + qt * 4 + wave) * 2) * 512 + lane * 8;
    f16x8 qa[2] = {*reinterpret_cast<const f16x8*>(qb),
                   *reinterpret_cast<const f16x8*>(qb + 512)};

    float shq[4];
    #pragma unroll
    for (int r = 0; r < 4; ++r) shq[r] = s_h[bh * S_ + q0 + rl + r];

    auto stageK = [&](int kt) {
        const _Float16* sh_ = Kfh + (size_t)((bh * 32 + kt * 4) * 2) * 512;
        const _Float16* sl_ = Kfl + (size_t)((bh * 32 + kt * 4) * 2) * 512;
        #pragma unroll
        for (int c = 0; c < 2; ++c) {
            int u = (c * 4 + wave) * 512;
            gload_lds16(&sh_[u + lane * 8], &Kst[0][u]);
            gload_lds16(&sl_[u + lane * 8], &Kst[1][u]);
        }
    };
    auto stageV = [&](int kt) {
        const _Float16* vh_ = Vfh + (size_t)((bh * 16 + kt * 2) * 4) * 512;
        const _Float16* vl_ = Vfl + (size_t)((bh * 16 + kt * 2) * 4) * 512;
        #pragma unroll
        for (int c = 0; c < 2; ++c) {
            int u = (c * 4 + wave) * 512;
            gload_lds16(&vh_[u + lane * 8], &Vst[0][u]);
            gload_lds16(&vl_[u + lane * 8], &Vst[1][u]);
        }
    };

    float m_r[4], l_r[4];
    f32x4 ctx[4];
    #pragma unroll
    for (int r = 0; r < 4; ++r) m_r[r] = -INFINITY, l_r[r] = 0.0f;
    #pragma unroll
    for (int fd = 0; fd < 4; ++fd) ctx[fd] = (f32x4){0.f, 0.f, 0.f, 0.f};

    stageK(0); stageV(0);
    __syncthreads();

    for (int kt = 0; kt < 8; ++kt) {
        float sc[4][4];
        __builtin_amdgcn_s_setprio(1);
        #pragma unroll
        for (int fc = 0; fc < 4; ++fc) {
            f16x8 kh[2] = {*reinterpret_cast<const f16x8*>(&Kst[0][(fc * 2 + 0) * 512 + lane * 8]),
                           *reinterpret_cast<const f16x8*>(&Kst[0][(fc * 2 + 1) * 512 + lane * 8])};
            f16x8 kl[2] = {*reinterpret_cast<const f16x8*>(&Kst[1][(fc * 2 + 0) * 512 + lane * 8]),
                           *reinterpret_cast<const f16x8*>(&Kst[1][(fc * 2 + 1) * 512 + lane * 8])};
            f32x4 acc = qk_dot(qa, kh, kl);
            int col = kt * 64 + fc * 16 + l15;
            float mj  = mask[b * S_ + col];
            float swj = s_w[bh * S_ + col];
            #pragma unroll
            for (int r = 0; r < 4; ++r) {
                float t1 = acc[r] >= 2048.0f ? 1.0f : 0.0f;
                sc[fc][r] = acc[r] * 4.8828125e-4f + mj + t1 * (shq[r] * swj);
            }
        }
        __builtin_amdgcn_s_setprio(0);
        __syncthreads();
        if (kt < 7) stageK(kt + 1);

        float p[4][4], cscale[4];
        #pragma unroll
        for (int r = 0; r < 4; ++r) {
            float tmax = fmaxf(fmaxf(sc[0][r], sc[1][r]), fmaxf(sc[2][r], sc[3][r]));
            tmax = fmaxf(tmax, __shfl_xor(tmax, 1));
            tmax = fmaxf(tmax, __shfl_xor(tmax, 2));
            tmax = fmaxf(tmax, __shfl_xor(tmax, 4));
            tmax = fmaxf(tmax, __shfl_xor(tmax, 8));
            float mn = fmaxf(m_r[r], tmax);
            float ps = 0.0f;
            #pragma unroll
            for (int fc = 0; fc < 4; ++fc) { p[fc][r] = expf(sc[fc][r] - mn); ps += p[fc][r]; }
            ps += __shfl_xor(ps, 1); ps += __shfl_xor(ps, 2);
            ps += __shfl_xor(ps, 4); ps += __shfl_xor(ps, 8);
            float scale = expf(m_r[r] - mn);
            l_r[r] = l_r[r] * scale + ps;
            m_r[r] = mn;
            cscale[r] = scale;
        }
        #pragma unroll
        for (int fc = 0; fc < 4; ++fc)
            #pragma unroll
            for (int r = 0; r < 4; ++r)
                P_lds[rl + r][fc * 16 + l15] = p[fc][r];

        f16x8 ph[2], pl[2];
        #pragma unroll
        for (int c = 0; c < 2; ++c) {
            f32x4 pa = *reinterpret_cast<const f32x4*>(&P_lds[wave * 16 + l15][c * 32 + g * 8]);
            f32x4 pb = *reinterpret_cast<const f32x4*>(&P_lds[wave * 16 + l15][c * 32 + g * 8 + 4]);
            float pv8[8] = {pa[0], pa[1], pa[2], pa[3], pb[0], pb[1], pb[2], pb[3]};
            #pragma unroll
            for (int j = 0; j < 8; ++j) {
                _Float16 hh = (_Float16)pv8[j];
                ph[c][j] = hh;
                pl[c][j] = (_Float16)(pv8[j] - (float)hh);
            }
        }
        #pragma unroll
        for (int fd = 0; fd < 4; ++fd)
            #pragma unroll
            for (int r = 0; r < 4; ++r) ctx[fd][r] *= cscale[r];

        __builtin_amdgcn_s_setprio(1);
        #pragma unroll
        for (int fd = 0; fd < 4; ++fd) {
            f16x8 vh0 = *reinterpret_cast<const f16x8*>(&Vst[0][(0 * 4 + fd) * 512 + lane * 8]);
            f16x8 vl0 = *reinterpret_cast<const f16x8*>(&Vst[1][(0 * 4 + fd) * 512 + lane * 8]);
            f16x8 vh1 = *reinterpret_cast<const f16x8*>(&Vst[0][(1 * 4 + fd) * 512 + lane * 8]);
            f16x8 vl1 = *reinterpret_cast<const f16x8*>(&Vst[1][(1 * 4 + fd) * 512 + lane * 8]);
            ctx[fd] = __builtin_amdgcn_mfma_f32_16x16x32_f16(ph[0], vh0, ctx[fd], 0, 0, 0);
            ctx[fd] = __builtin_amdgcn_mfma_f32_16x16x32_f16(ph[0], vl0, ctx[fd], 0, 0, 0);
            ctx[fd] = __builtin_amdgcn_mfma_f32_16x16x32_f16(pl[0], vh0, ctx[fd], 0, 0, 0);
            ctx[fd] = __builtin_amdgcn_mfma_f32_16x16x32_f16(ph[1], vh1, ctx[fd], 0, 0, 0);
            ctx[fd] = __builtin_amdgcn_mfma_f32_16x16x32_f16(ph[1], vl1, ctx[fd], 0, 0, 0);
            ctx[fd] = __builtin_amdgcn_mfma_f32_16x16x32_f16(pl[1], vh1, ctx[fd], 0, 0, 0);
        }
        __builtin_amdgcn_s_setprio(0);
        __syncthreads();
        if (kt < 7) stageV(kt + 1);
    }
    #pragma unroll
    for (int r = 0; r < 4; ++r) {
        int s = q0 + rl + r;
        float inv = 1.0f / l_r[r];
        float* orow = &out[((size_t)b * S_ + s) * DM_ + h * D_];
        #pragma unroll
        for (int fd = 0; fd < 4; ++fd)
            orow[fd * 16 + l15] = ctx[fd][r] * inv;
    }
}

extern "C" void kernel_launch(void* const* d_in, const int* in_sizes, int n_in,
                              void* d_out, int out_size, void* d_ws, size_t ws_size,
                              hipStream_t stream) {
    const float* X    = (const float*)d_in[0];
    const float* mask = (const float*)d_in[1];
    const float* Wq   = (const float*)d_in[2];
    const float* bq   = (const float*)d_in[3];
    const float* Wk   = (const float*)d_in[4];
    const float* bk   = (const float*)d_in[5];
    const float* Wv   = (const float*)d_in[6];
    const float* bv   = (const float*)d_in[7];
    const float* c1w  = (const float*)d_in[8];
    const float* gam  = (const float*)d_in[9];
    const float* bet  = (const float*)d_in[10];
    const float* chw  = (const float*)d_in[11];
    const float* cww  = (const float*)d_in[12];
    float* out = (float*)d_out;

    float* ws = (float*)d_ws;
    // Fragments live in the former q/k/v fp32 regions (no fp32 round-trip):
    _Float16* Qf  = (_Float16*)ws;                 // 6.3 MB (q region, 12.6 MB)
    float* stats_part = (float*)(Qf + 3145728);    // 48 floats, q region spare
    _Float16* Kfh = (_Float16*)(ws + 3145728);     // k region
    _Float16* Kfl = Kfh + 3145728;
    _Float16* Vfh = (_Float16*)(ws + 2 * 3145728); // v region
    _Float16* Vfl = Vfh + 3145728;
    float* xh = ws + 3 * 3145728;                  // 49152
    float* xw = xh + 49152;
    float* y  = xw + 49152;                        // 24576
    float* sh = y  + 24576;
    float* sw = sh + 49152;
    _Float16* Xh  = (_Float16*)(sw + 49152);       // 3145728 halves (staging)
    _Float16* Xl  = Xh + 3145728;
    _Float16* Wth = Xl + 3145728;                  // 1769472 halves
    _Float16* Wtl = Wth + 1769472;                 // total ws ~55.6 MiB

    hipMemsetAsync(xw, 0, 49152 * sizeof(float), stream);

    prep_x<<<1536, 256, 0, stream>>>(X, Xh, Xl);
    prep_w<<<864, 256, 0, stream>>>(Wq, Wk, Wv, Wth, Wtl);
    qkv_mfma<<<768, 512, 0, stream>>>(Xh, Xl, Wth, Wtl,
        X, Wq, bq, Wk, bk, Wv, bv, Qf, Kfh, Kfl, Vfh, Vfl);
    score_sums<<<768, 256, 0, stream>>>(Qf, Kfh, Kfl, xh, xw);
    small_a<<<24, 256, 0, stream>>>(xh, xw, c1w, y, stats_part);
    small_b<<<96, 512, 0, stream>>>(y, stats_part, gam, bet, chw, cww, sh, sw);
    attn_pv<<<768, 256, 0, stream>>>(Qf, Kfh, Kfl, Vfh, Vfl, mask, sh, sw, out);
}

// Round 16
// 137.991 us; speedup vs baseline: 1.0812x; 1.0812x over previous
//
#include <hip/hip_runtime.h>
#include <math.h>

#define B_   8
#define S_   512
#define DM_  768
#define H_   12
#define D_   64
#define BH_  96
#define M_   4096   // B_*S_

typedef _Float16 f16x8 __attribute__((ext_vector_type(8)));
typedef _Float16 f16x4 __attribute__((ext_vector_type(4)));
typedef float    f32x4 __attribute__((ext_vector_type(4)));

__device__ __forceinline__ float dual_spike(float x) {
    return x >= 1.0f ? 1.0f : (x <= -1.0f ? -1.0f : 0.0f);
}

__device__ __forceinline__ void gload_lds16(const void* g, void* l) {
    __builtin_amdgcn_global_load_lds(
        (const __attribute__((address_space(1))) unsigned int*)g,
        (__attribute__((address_space(3))) unsigned int*)l, 16, 0, 0);
}

// Shared QK dot chain — MUST be bitwise identical wherever t is derived.
__device__ __forceinline__ f32x4 qk_dot(const f16x8* qa, const f16x8* kh, const f16x8* kl) {
    f32x4 acc = (f32x4){0.f, 0.f, 0.f, 0.f};
    acc = __builtin_amdgcn_mfma_f32_16x16x32_f16(qa[0], kh[0], acc, 0, 0, 0);
    acc = __builtin_amdgcn_mfma_f32_16x16x32_f16(qa[0], kl[0], acc, 0, 0, 0);
    acc = __builtin_amdgcn_mfma_f32_16x16x32_f16(qa[1], kh[1], acc, 0, 0, 0);
    acc = __builtin_amdgcn_mfma_f32_16x16x32_f16(qa[1], kl[1], acc, 0, 0, 0);
    return acc;
}

// ---------------- Prepass (fused): X and W -> fp16 hi/lo planes -----------------
// Blocks 0..1535: X -> FLAT [kc 24][fm 256][512]; blocks 1536..2399: W (q,k,v)
// -> transposed FLAT [which 3][kc 24][fn 48][512]. Arithmetic identical to the
// separate prep_x/prep_w kernels (R14); fusion only saves a launch.
__global__ __launch_bounds__(256) void prep_xw(
    const float* __restrict__ X,
    const float* __restrict__ Wq, const float* __restrict__ Wk, const float* __restrict__ Wv,
    _Float16* __restrict__ Xh, _Float16* __restrict__ Xl,
    _Float16* __restrict__ Wth, _Float16* __restrict__ Wtl)
{
    int lane = threadIdx.x & 63;
    if (blockIdx.x < 1536) {
        int wid  = blockIdx.x * 4 + (threadIdx.x >> 6);   // 0..6143
        int fm = wid & 255, kc = wid >> 8;
        int row = fm * 16 + (lane & 15);
        int col = kc * 32 + (lane >> 4) * 8;
        const float4* p = reinterpret_cast<const float4*>(&X[row * DM_ + col]);
        float4 x0 = p[0], x1 = p[1];
        float xs[8] = {x0.x, x0.y, x0.z, x0.w, x1.x, x1.y, x1.z, x1.w};
        f16x8 hi, lo;
        #pragma unroll
        for (int j = 0; j < 8; ++j) {
            float v = xs[j] * 256.0f;
            _Float16 h = (_Float16)v;
            hi[j] = h;
            lo[j] = (_Float16)(v - (float)h);
        }
        size_t out = ((size_t)wid * 64 + lane) * 8;
        *reinterpret_cast<f16x8*>(&Xh[out]) = hi;
        *reinterpret_cast<f16x8*>(&Xl[out]) = lo;
    } else {
        int wid  = (blockIdx.x - 1536) * 4 + (threadIdx.x >> 6);   // 0..3455
        int fn = wid % 48, kc = (wid / 48) % 24, which = wid / 1152;
        const float* __restrict__ W = which == 0 ? Wq : (which == 1 ? Wk : Wv);
        int c = lane & 15, g = lane >> 4;
        int ncol = fn * 16 + c;
        int krow = kc * 32 + g * 8;
        f16x8 hi, lo;
        #pragma unroll
        for (int j = 0; j < 8; ++j) {
            float v = W[(krow + j) * DM_ + ncol] * 256.0f;
            _Float16 h = (_Float16)v;
            hi[j] = h;
            lo[j] = (_Float16)(v - (float)h);
        }
        size_t out = ((size_t)wid * 64 + lane) * 8;
        *reinterpret_cast<f16x8*>(&Wth[out]) = hi;
        *reinterpret_cast<f16x8*>(&Wtl[out]) = lo;
    }
}

// ---------------- Kernel 1: QKV via fp16 split MFMA, LDS-staged dbuf -----------
// R14 known-good (140.5us total): 128x96 tile, 512 threads (8 waves, wave=32x48,
// acc[2][3]), 28KB dbuf, one __syncthreads per iter, fused fragment epilogue.
// R15's counted-vmcnt double-barrier variant REGRESSED (76us) — reverted.
__global__ __launch_bounds__(512, 4) void qkv_mfma(
    const _Float16* __restrict__ Xh, const _Float16* __restrict__ Xl,
    const _Float16* __restrict__ Wth, const _Float16* __restrict__ Wtl,
    const float* __restrict__ X,
    const float* __restrict__ Wq, const float* __restrict__ bq,
    const float* __restrict__ Wk, const float* __restrict__ bk,
    const float* __restrict__ Wv, const float* __restrict__ bv,
    _Float16* __restrict__ Qf, _Float16* __restrict__ Kfh, _Float16* __restrict__ Kfl,
    _Float16* __restrict__ Vfh, _Float16* __restrict__ Vfl)
{
    // XCD epochs: per XCD 3 epochs x (4 mb x 8 nb) of one which.
    const int orig = blockIdx.x;
    const int xcd = orig & 7, idx = orig >> 3;        // idx 0..95
    const int epoch = idx >> 5, sub = idx & 31;       // 3 epochs x 32 blocks
    const int mw = xcd * 12 + epoch * 4 + (sub >> 3); // 0..95 bijective
    const int which = mw / 32, mb = mw % 32;
    const int nb = sub & 7;                           // 0..7 (96-col panels)

    const float* __restrict__ bias = which == 0 ? bq : (which == 1 ? bk : bv);

    // [buf][Ah 4096 | Al 4096 | Bh 3072 | Bl 3072] halves = 28KB/buf
    __shared__ __align__(16) _Float16 lds[2][14336];

    const int tid = threadIdx.x;
    const int wave = tid >> 6, lane = tid & 63;
    const int wm = wave >> 1, wn = wave & 1;          // wm 0..3, wn 0..1
    const int l15 = lane & 15, g = lane >> 4;

    auto stage = [&](int kc, int bsel) {
        #pragma unroll
        for (int c = 0; c < 4; ++c) {
            int u = wave * 4 + c;                     // 0..31; units 0..27 valid
            if (u < 28) {
                const _Float16* src;
                if (u < 8)       src = Xh  + (size_t)(kc * 256 + mb * 8 + u) * 512;
                else if (u < 16) src = Xl  + (size_t)(kc * 256 + mb * 8 + (u - 8)) * 512;
                else if (u < 22) src = Wth + (size_t)((which * 24 + kc) * 48 + nb * 6 + (u - 16)) * 512;
                else             src = Wtl + (size_t)((which * 24 + kc) * 48 + nb * 6 + (u - 22)) * 512;
                gload_lds16(src + lane * 8, &lds[bsel][u * 512]);
            }
        }
    };

    f32x4 acc[2][3];
    #pragma unroll
    for (int i = 0; i < 2; ++i)
        #pragma unroll
        for (int j = 0; j < 3; ++j) acc[i][j] = (f32x4){0.f, 0.f, 0.f, 0.f};

    stage(0, 0);
    __syncthreads();
    int cur = 0;

    for (int kc = 0; kc < 24; ++kc) {
        if (kc + 1 < 24) stage(kc + 1, cur ^ 1);     // prefetch flies under compute
        const _Float16* Bf = lds[cur];
        f16x8 ah[2], al[2], bh[3], bl[3];
        #pragma unroll
        for (int f = 0; f < 2; ++f) {
            ah[f] = *reinterpret_cast<const f16x8*>(&Bf[(wm * 2 + f) * 512 + lane * 8]);
            al[f] = *reinterpret_cast<const f16x8*>(&Bf[4096 + (wm * 2 + f) * 512 + lane * 8]);
        }
        #pragma unroll
        for (int fb = 0; fb < 3; ++fb) {
            bh[fb] = *reinterpret_cast<const f16x8*>(&Bf[8192 + (wn * 3 + fb) * 512 + lane * 8]);
            bl[fb] = *reinterpret_cast<const f16x8*>(&Bf[11264 + (wn * 3 + fb) * 512 + lane * 8]);
        }
        __builtin_amdgcn_s_setprio(1);
        #pragma unroll
        for (int i = 0; i < 2; ++i)
            #pragma unroll
            for (int j = 0; j < 3; ++j) {
                acc[i][j] = __builtin_amdgcn_mfma_f32_16x16x32_f16(ah[i], bh[j], acc[i][j], 0, 0, 0);
                acc[i][j] = __builtin_amdgcn_mfma_f32_16x16x32_f16(ah[i], bl[j], acc[i][j], 0, 0, 0);
                acc[i][j] = __builtin_amdgcn_mfma_f32_16x16x32_f16(al[i], bh[j], acc[i][j], 0, 0, 0);
            }
        __builtin_amdgcn_s_setprio(0);
        __syncthreads();                              // drains prefetch; buffers swap
        cur ^= 1;
    }

    const float* __restrict__ Worig = which == 0 ? Wq : (which == 1 ? Wk : Wv);

    #pragma unroll
    for (int i = 0; i < 2; ++i) {
        #pragma unroll
        for (int j = 0; j < 3; ++j) {
            int n = nb * 96 + wn * 48 + j * 16 + l15;
            int h = n >> 6, d = n & 63;
            float bn = bias[n];
            float vals[4];
            #pragma unroll
            for (int r = 0; r < 4; ++r) {
                float val = acc[i][j][r] * (1.0f / 65536.0f) + bn;
                if (which < 2) {
                    bool need = fabsf(fabsf(val) - 1.0f) < 1e-4f;
                    unsigned long long msk = __ballot(need);
                    // wave-parallel deterministic recompute per flagged lane
                    while (msk) {
                        int L = (int)__builtin_ctzll(msk);
                        msk &= msk - 1;
                        int Lm = mb * 128 + wm * 32 + i * 16 + (L >> 4) * 4 + r;
                        int Ln = nb * 96 + wn * 48 + j * 16 + (L & 15);
                        const float* xr = X + (size_t)Lm * DM_;
                        const float* wc = Worig + Ln;
                        float xs[12], wsv[12];
                        #pragma unroll
                        for (int t = 0; t < 12; ++t) {
                            int e = t * 64 + lane;
                            xs[t]  = xr[e];
                            wsv[t] = wc[(size_t)e * DM_];
                        }
                        float part = 0.0f;
                        #pragma unroll
                        for (int t = 0; t < 12; ++t) part = fmaf(xs[t], wsv[t], part);
                        part += __shfl_xor(part, 1);
                        part += __shfl_xor(part, 2);
                        part += __shfl_xor(part, 4);
                        part += __shfl_xor(part, 8);
                        part += __shfl_xor(part, 16);
                        part += __shfl_xor(part, 32);
                        if (lane == L) val = part + bn;
                    }
                }
                vals[r] = val;
            }
            int m0 = mb * 128 + wm * 32 + i * 16 + g * 4;   // s for r=0
            int b = m0 >> 9, s0 = m0 & 511;
            int bh_ = b * H_ + h;
            if (which == 0) {
                #pragma unroll
                for (int r = 0; r < 4; ++r) {
                    int s = s0 + r;
                    size_t unit = (size_t)(bh_ * 32 + (s >> 4)) * 2 + (d >> 5);
                    size_t off = unit * 512 + (size_t)(((d >> 3) & 3) * 16 + (s & 15)) * 8 + (d & 7);
                    Qf[off] = (_Float16)dual_spike(vals[r]);
                }
            } else if (which == 1) {
                #pragma unroll
                for (int r = 0; r < 4; ++r) {
                    int s = s0 + r;
                    float kv = 0.5f * dual_spike(vals[r]) + 0.5f * vals[r];
                    float sv = kv * 256.0f;
                    _Float16 hh = (_Float16)sv;
                    size_t unit = (size_t)(bh_ * 32 + (s >> 4)) * 2 + (d >> 5);
                    size_t off = unit * 512 + (size_t)(((d >> 3) & 3) * 16 + (s & 15)) * 8 + (d & 7);
                    Kfh[off] = hh;
                    Kfl[off] = (_Float16)(sv - (float)hh);
                }
            } else {
                f16x4 ph4, pl4;
                #pragma unroll
                for (int r = 0; r < 4; ++r) {
                    _Float16 hh = (_Float16)vals[r];
                    ph4[r] = hh;
                    pl4[r] = (_Float16)(vals[r] - (float)hh);
                }
                size_t unit = (size_t)(bh_ * 16 + (s0 >> 5)) * 4 + (d >> 4);
                size_t off = unit * 512 + (size_t)(((s0 >> 3) & 3) * 16 + (d & 15)) * 8 + (s0 & 7);
                *reinterpret_cast<f16x4*>(&Vfh[off]) = ph4;
                *reinterpret_cast<f16x4*>(&Vfl[off]) = pl4;
            }
        }
    }
}

// ---------------- Kernel 2: score threshold counts via MFMA --------------------
__global__ __launch_bounds__(256) void score_sums(
    const _Float16* __restrict__ Qf, const _Float16* __restrict__ Kfh,
    const _Float16* __restrict__ Kfl,
    float* __restrict__ xh, float* __restrict__ xw)
{
    const int orig = blockIdx.x;
    const int xcd = orig & 7, idx = orig >> 3;
    const int bh = xcd * 12 + idx / 8, qt = idx & 7;
    const int tid = threadIdx.x, wave = tid >> 6, lane = tid & 63;
    const int l15 = lane & 15, g = lane >> 4;

    __shared__ float rowred[4][64];

    f16x8 qa[4][2];
    #pragma unroll
    for (int sf = 0; sf < 4; ++sf) {
        const _Float16* qb = Qf + (size_t)((bh * 32 + qt * 4 + sf) * 2) * 512 + lane * 8;
        qa[sf][0] = *reinterpret_cast<const f16x8*>(qb);
        qa[sf][1] = *reinterpret_cast<const f16x8*>(qb + 512);
    }
    float rowc[4][4];
    #pragma unroll
    for (int sf = 0; sf < 4; ++sf)
        #pragma unroll
        for (int r = 0; r < 4; ++r) rowc[sf][r] = 0.0f;

    for (int sc8 = 0; sc8 < 8; ++sc8) {
        int scol16 = sc8 * 4 + wave;
        const _Float16* kbh = Kfh + (size_t)((bh * 32 + scol16) * 2) * 512 + lane * 8;
        const _Float16* kbl = Kfl + (size_t)((bh * 32 + scol16) * 2) * 512 + lane * 8;
        f16x8 kh[2] = {*reinterpret_cast<const f16x8*>(kbh),
                       *reinterpret_cast<const f16x8*>(kbh + 512)};
        f16x8 kl[2] = {*reinterpret_cast<const f16x8*>(kbl),
                       *reinterpret_cast<const f16x8*>(kbl + 512)};
        float csum = 0.0f;
        #pragma unroll
        for (int sf = 0; sf < 4; ++sf) {
            f32x4 acc = qk_dot(qa[sf], kh, kl);
            #pragma unroll
            for (int r = 0; r < 4; ++r) {
                float t1 = acc[r] >= 2048.0f ? 1.0f : 0.0f;   // dot >= 8
                rowc[sf][r] += t1;
                csum += t1;
            }
        }
        csum += __shfl_xor(csum, 16);
        csum += __shfl_xor(csum, 32);
        if (g == 0) atomicAdd(&xw[bh * S_ + scol16 * 16 + l15], csum);
    }
    #pragma unroll
    for (int sf = 0; sf < 4; ++sf)
        #pragma unroll
        for (int r = 0; r < 4; ++r) {
            float sv = rowc[sf][r];
            sv += __shfl_xor(sv, 1); sv += __shfl_xor(sv, 2);
            sv += __shfl_xor(sv, 4); sv += __shfl_xor(sv, 8);
            if (l15 == 0) rowred[wave][sf * 16 + g * 4 + r] = sv;
        }
    __syncthreads();
    if (tid < 64) {
        float sv = rowred[0][tid] + rowred[1][tid] + rowred[2][tid] + rowred[3][tid];
        xh[bh * S_ + qt * 64 + tid] = sv;    // exact count, no atomics needed
    }
}

// ---------------- Kernel 3a: conv1 y + per-block partial stats (deterministic) --
__global__ __launch_bounds__(256) void small_a(
    const float* __restrict__ xh, const float* __restrict__ xw,
    const float* __restrict__ c1w,
    float* __restrict__ y, float* __restrict__ stats_part)   // [24][2]
{
    const int tid = threadIdx.x;
    const int br = blockIdx.x;           // b*3 + r
    const int r = br % 3, b = br / 3;
    __shared__ float c1s[12];
    __shared__ float red[256], red2[256];
    if (tid < 12) c1s[tid] = c1w[r * 12 + tid];
    __syncthreads();

    float psum = 0.0f, psq = 0.0f;
    for (int n = tid; n < 1024; n += 256) {
        float acc = 0.0f;
        #pragma unroll
        for (int h = 0; h < 12; ++h) {
            float cv = (n < 512) ? xh[(b * H_ + h) * S_ + n]
                                 : xw[(b * H_ + h) * S_ + (n - 512)];
            acc = fmaf(c1s[h], cv * (1.0f / 512.0f), acc);
        }
        y[br * 1024 + n] = acc;
        psum += acc;
        psq = fmaf(acc, acc, psq);
    }
    red[tid] = psum; red2[tid] = psq;
    __syncthreads();
    for (int o = 128; o > 0; o >>= 1) {
        if (tid < o) { red[tid] += red[tid + o]; red2[tid] += red2[tid + o]; }
        __syncthreads();
    }
    if (tid == 0) {
        stats_part[br * 2 + 0] = red[0];
        stats_part[br * 2 + 1] = red2[0];
    }
}

// ---------------- Kernel 3b: BN + relu + conv + sigmoid ------------------------
__global__ __launch_bounds__(512) void small_b(
    const float* __restrict__ y, const float* __restrict__ stats_part,
    const float* __restrict__ gamma, const float* __restrict__ beta,
    const float* __restrict__ chw, const float* __restrict__ cww,
    float* __restrict__ s_h, float* __restrict__ s_w)
{
    int e = blockIdx.x * 512 + threadIdx.x;   // 0..49151
    int s = e & 511; int bh = e >> 9; int h = bh % H_; int b = bh / H_;
    float ah = 0.0f, aw = 0.0f;
    #pragma unroll
    for (int r = 0; r < 3; ++r) {
        float su = 0.0f, sq = 0.0f;
        #pragma unroll
        for (int bb = 0; bb < 8; ++bb) {     // fixed order -> deterministic
            su += stats_part[(bb * 3 + r) * 2 + 0];
            sq += stats_part[(bb * 3 + r) * 2 + 1];
        }
        float mu = su * (1.0f / 8192.0f);
        float var = sq * (1.0f / 8192.0f) - mu * mu;
        float rs = rsqrtf(var + 1e-5f);
        int yb = (b * 3 + r) << 10;
        float yh = fmaxf((y[yb + s]       - mu) * rs * gamma[r] + beta[r], 0.0f);
        float yw = fmaxf((y[yb + 512 + s] - mu) * rs * gamma[r] + beta[r], 0.0f);
        ah = fmaf(chw[h * 3 + r], yh, ah);
        aw = fmaf(cww[h * 3 + r], yw, aw);
    }
    s_h[e] = 1.0f / (1.0f + expf(-ah));
    s_w[e] = 1.0f / (1.0f + expf(-aw));
}

// ---------------- Kernel 4: full-MFMA attention (R13/R14, unchanged) ------------
__global__ __launch_bounds__(256) void attn_pv(
    const _Float16* __restrict__ Qf, const _Float16* __restrict__ Kfh,
    const _Float16* __restrict__ Kfl,
    const _Float16* __restrict__ Vfh, const _Float16* __restrict__ Vfl,
    const float* __restrict__ mask, const float* __restrict__ s_h,
    const float* __restrict__ s_w, float* __restrict__ out)
{
    __shared__ __align__(16) _Float16 Kst[2][4096];
    __shared__ __align__(16) _Float16 Vst[2][4096];
    __shared__ __align__(16) float P_lds[64][68];

    const int orig = blockIdx.x;
    const int xcd = orig & 7, idx = orig >> 3;
    const int bh = xcd * 12 + idx / 8, qt = idx & 7;
    const int b = bh / H_, h = bh % H_;
    const int q0 = qt * 64;
    const int tid = threadIdx.x, wave = tid >> 6, lane = tid & 63;
    const int l15 = lane & 15, g = lane >> 4;
    const int rl = wave * 16 + g * 4;

    const _Float16* qb = Qf + (size_t)((bh * 32 + qt * 4 + wave) * 2) * 512 + lane * 8;
    f16x8 qa[2] = {*reinterpret_cast<const f16x8*>(qb),
                   *reinterpret_cast<const f16x8*>(qb + 512)};

    float shq[4];
    #pragma unroll
    for (int r = 0; r < 4; ++r) shq[r] = s_h[bh * S_ + q0 + rl + r];

    auto stageK = [&](int kt) {
        const _Float16* sh_ = Kfh + (size_t)((bh * 32 + kt * 4) * 2) * 512;
        const _Float16* sl_ = Kfl + (size_t)((bh * 32 + kt * 4) * 2) * 512;
        #pragma unroll
        for (int c = 0; c < 2; ++c) {
            int u = (c * 4 + wave) * 512;
            gload_lds16(&sh_[u + lane * 8], &Kst[0][u]);
            gload_lds16(&sl_[u + lane * 8], &Kst[1][u]);
        }
    };
    auto stageV = [&](int kt) {
        const _Float16* vh_ = Vfh + (size_t)((bh * 16 + kt * 2) * 4) * 512;
        const _Float16* vl_ = Vfl + (size_t)((bh * 16 + kt * 2) * 4) * 512;
        #pragma unroll
        for (int c = 0; c < 2; ++c) {
            int u = (c * 4 + wave) * 512;
            gload_lds16(&vh_[u + lane * 8], &Vst[0][u]);
            gload_lds16(&vl_[u + lane * 8], &Vst[1][u]);
        }
    };

    float m_r[4], l_r[4];
    f32x4 ctx[4];
    #pragma unroll
    for (int r = 0; r < 4; ++r) m_r[r] = -INFINITY, l_r[r] = 0.0f;
    #pragma unroll
    for (int fd = 0; fd < 4; ++fd) ctx[fd] = (f32x4){0.f, 0.f, 0.f, 0.f};

    stageK(0); stageV(0);
    __syncthreads();

    for (int kt = 0; kt < 8; ++kt) {
        float sc[4][4];
        __builtin_amdgcn_s_setprio(1);
        #pragma unroll
        for (int fc = 0; fc < 4; ++fc) {
            f16x8 kh[2] = {*reinterpret_cast<const f16x8*>(&Kst[0][(fc * 2 + 0) * 512 + lane * 8]),
                           *reinterpret_cast<const f16x8*>(&Kst[0][(fc * 2 + 1) * 512 + lane * 8])};
            f16x8 kl[2] = {*reinterpret_cast<const f16x8*>(&Kst[1][(fc * 2 + 0) * 512 + lane * 8]),
                           *reinterpret_cast<const f16x8*>(&Kst[1][(fc * 2 + 1) * 512 + lane * 8])};
            f32x4 acc = qk_dot(qa, kh, kl);
            int col = kt * 64 + fc * 16 + l15;
            float mj  = mask[b * S_ + col];
            float swj = s_w[bh * S_ + col];
            #pragma unroll
            for (int r = 0; r < 4; ++r) {
                float t1 = acc[r] >= 2048.0f ? 1.0f : 0.0f;
                sc[fc][r] = acc[r] * 4.8828125e-4f + mj + t1 * (shq[r] * swj);
            }
        }
        __builtin_amdgcn_s_setprio(0);
        __syncthreads();
        if (kt < 7) stageK(kt + 1);

        float p[4][4], cscale[4];
        #pragma unroll
        for (int r = 0; r < 4; ++r) {
            float tmax = fmaxf(fmaxf(sc[0][r], sc[1][r]), fmaxf(sc[2][r], sc[3][r]));
            tmax = fmaxf(tmax, __shfl_xor(tmax, 1));
            tmax = fmaxf(tmax, __shfl_xor(tmax, 2));
            tmax = fmaxf(tmax, __shfl_xor(tmax, 4));
            tmax = fmaxf(tmax, __shfl_xor(tmax, 8));
            float mn = fmaxf(m_r[r], tmax);
            float ps = 0.0f;
            #pragma unroll
            for (int fc = 0; fc < 4; ++fc) { p[fc][r] = expf(sc[fc][r] - mn); ps += p[fc][r]; }
            ps += __shfl_xor(ps, 1); ps += __shfl_xor(ps, 2);
            ps += __shfl_xor(ps, 4); ps += __shfl_xor(ps, 8);
            float scale = expf(m_r[r] - mn);
            l_r[r] = l_r[r] * scale + ps;
            m_r[r] = mn;
            cscale[r] = scale;
        }
        #pragma unroll
        for (int fc = 0; fc < 4; ++fc)
            #pragma unroll
            for (int r = 0; r < 4; ++r)
                P_lds[rl + r][fc * 16 + l15] = p[fc][r];

        f16x8 ph[2], pl[2];
        #pragma unroll
        for (int c = 0; c < 2; ++c) {
            f32x4 pa = *reinterpret_cast<const f32x4*>(&P_lds[wave * 16 + l15][c * 32 + g * 8]);
            f32x4 pb = *reinterpret_cast<const f32x4*>(&P_lds[wave * 16 + l15][c * 32 + g * 8 + 4]);
            float pv8[8] = {pa[0], pa[1], pa[2], pa[3], pb[0], pb[1], pb[2], pb[3]};
            #pragma unroll
            for (int j = 0; j < 8; ++j) {
                _Float16 hh = (_Float16)pv8[j];
                ph[c][j] = hh;
                pl[c][j] = (_Float16)(pv8[j] - (float)hh);
            }
        }
        #pragma unroll
        for (int fd = 0; fd < 4; ++fd)
            #pragma unroll
            for (int r = 0; r < 4; ++r) ctx[fd][r] *= cscale[r];

        __builtin_amdgcn_s_setprio(1);
        #pragma unroll
        for (int fd = 0; fd < 4; ++fd) {
            f16x8 vh0 = *reinterpret_cast<const f16x8*>(&Vst[0][(0 * 4 + fd) * 512 + lane * 8]);
            f16x8 vl0 = *reinterpret_cast<const f16x8*>(&Vst[1][(0 * 4 + fd) * 512 + lane * 8]);
            f16x8 vh1 = *reinterpret_cast<const f16x8*>(&Vst[0][(1 * 4 + fd) * 512 + lane * 8]);
            f16x8 vl1 = *reinterpret_cast<const f16x8*>(&Vst[1][(1 * 4 + fd) * 512 + lane * 8]);
            ctx[fd] = __builtin_amdgcn_mfma_f32_16x16x32_f16(ph[0], vh0, ctx[fd], 0, 0, 0);
            ctx[fd] = __builtin_amdgcn_mfma_f32_16x16x32_f16(ph[0], vl0, ctx[fd], 0, 0, 0);
            ctx[fd] = __builtin_amdgcn_mfma_f32_16x16x32_f16(pl[0], vh0, ctx[fd], 0, 0, 0);
            ctx[fd] = __builtin_amdgcn_mfma_f32_16x16x32_f16(ph[1], vh1, ctx[fd], 0, 0, 0);
            ctx[fd] = __builtin_amdgcn_mfma_f32_16x16x32_f16(ph[1], vl1, ctx[fd], 0, 0, 0);
            ctx[fd] = __builtin_amdgcn_mfma_f32_16x16x32_f16(pl[1], vh1, ctx[fd], 0, 0, 0);
        }
        __builtin_amdgcn_s_setprio(0);
        __syncthreads();
        if (kt < 7) stageV(kt + 1);
    }
    #pragma unroll
    for (int r = 0; r < 4; ++r) {
        int s = q0 + rl + r;
        float inv = 1.0f / l_r[r];
        float* orow = &out[((size_t)b * S_ + s) * DM_ + h * D_];
        #pragma unroll
        for (int fd = 0; fd < 4; ++fd)
            orow[fd * 16 + l15] = ctx[fd][r] * inv;
    }
}

extern "C" void kernel_launch(void* const* d_in, const int* in_sizes, int n_in,
                              void* d_out, int out_size, void* d_ws, size_t ws_size,
                              hipStream_t stream) {
    const float* X    = (const float*)d_in[0];
    const float* mask = (const float*)d_in[1];
    const float* Wq   = (const float*)d_in[2];
    const float* bq   = (const float*)d_in[3];
    const float* Wk   = (const float*)d_in[4];
    const float* bk   = (const float*)d_in[5];
    const float* Wv   = (const float*)d_in[6];
    const float* bv   = (const float*)d_in[7];
    const float* c1w  = (const float*)d_in[8];
    const float* gam  = (const float*)d_in[9];
    const float* bet  = (const float*)d_in[10];
    const float* chw  = (const float*)d_in[11];
    const float* cww  = (const float*)d_in[12];
    float* out = (float*)d_out;

    float* ws = (float*)d_ws;
    // Fragments live in the former q/k/v fp32 regions (no fp32 round-trip):
    _Float16* Qf  = (_Float16*)ws;                 // 6.3 MB (q region, 12.6 MB)
    float* stats_part = (float*)(Qf + 3145728);    // 48 floats, q region spare
    _Float16* Kfh = (_Float16*)(ws + 3145728);     // k region
    _Float16* Kfl = Kfh + 3145728;
    _Float16* Vfh = (_Float16*)(ws + 2 * 3145728); // v region
    _Float16* Vfl = Vfh + 3145728;
    float* xh = ws + 3 * 3145728;                  // 49152
    float* xw = xh + 49152;
    float* y  = xw + 49152;                        // 24576
    float* sh = y  + 24576;
    float* sw = sh + 49152;
    _Float16* Xh  = (_Float16*)(sw + 49152);       // 3145728 halves (staging)
    _Float16* Xl  = Xh + 3145728;
    _Float16* Wth = Xl + 3145728;                  // 1769472 halves
    _Float16* Wtl = Wth + 1769472;                 // total ws ~55.6 MiB

    hipMemsetAsync(xw, 0, 49152 * sizeof(float), stream);

    prep_xw<<<2400, 256, 0, stream>>>(X, Wq, Wk, Wv, Xh, Xl, Wth, Wtl);
    qkv_mfma<<<768, 512, 0, stream>>>(Xh, Xl, Wth, Wtl,
        X, Wq, bq, Wk, bk, Wv, bv, Qf, Kfh, Kfl, Vfh, Vfl);
    score_sums<<<768, 256, 0, stream>>>(Qf, Kfh, Kfl, xh, xw);
    small_a<<<24, 256, 0, stream>>>(xh, xw, c1w, y, stats_part);
    small_b<<<96, 512, 0, stream>>>(y, stats_part, gam, bet, chw, cww, sh, sw);
    attn_pv<<<768, 256, 0, stream>>>(Qf, Kfh, Kfl, Vfh, Vfl, mask, sh, sw, out);
}

// Round 17
// 137.594 us; speedup vs baseline: 1.0844x; 1.0029x over previous
//
#include <hip/hip_runtime.h>
#include <math.h>

#define B_   8
#define S_   512
#define DM_  768
#define H_   12
#define D_   64
#define BH_  96
#define M_   4096   // B_*S_

typedef _Float16 f16x8 __attribute__((ext_vector_type(8)));
typedef _Float16 f16x4 __attribute__((ext_vector_type(4)));
typedef float    f32x4 __attribute__((ext_vector_type(4)));

__device__ __forceinline__ float dual_spike(float x) {
    return x >= 1.0f ? 1.0f : (x <= -1.0f ? -1.0f : 0.0f);
}

__device__ __forceinline__ void gload_lds16(const void* g, void* l) {
    __builtin_amdgcn_global_load_lds(
        (const __attribute__((address_space(1))) unsigned int*)g,
        (__attribute__((address_space(3))) unsigned int*)l, 16, 0, 0);
}

// Shared QK dot chain — MUST be bitwise identical wherever t is derived.
__device__ __forceinline__ f32x4 qk_dot(const f16x8* qa, const f16x8* kh, const f16x8* kl) {
    f32x4 acc = (f32x4){0.f, 0.f, 0.f, 0.f};
    acc = __builtin_amdgcn_mfma_f32_16x16x32_f16(qa[0], kh[0], acc, 0, 0, 0);
    acc = __builtin_amdgcn_mfma_f32_16x16x32_f16(qa[0], kl[0], acc, 0, 0, 0);
    acc = __builtin_amdgcn_mfma_f32_16x16x32_f16(qa[1], kh[1], acc, 0, 0, 0);
    acc = __builtin_amdgcn_mfma_f32_16x16x32_f16(qa[1], kl[1], acc, 0, 0, 0);
    return acc;
}

// ---------------- Prepass (fused): X and W -> fp16 hi/lo planes -----------------
__global__ __launch_bounds__(256) void prep_xw(
    const float* __restrict__ X,
    const float* __restrict__ Wq, const float* __restrict__ Wk, const float* __restrict__ Wv,
    _Float16* __restrict__ Xh, _Float16* __restrict__ Xl,
    _Float16* __restrict__ Wth, _Float16* __restrict__ Wtl)
{
    int lane = threadIdx.x & 63;
    if (blockIdx.x < 1536) {
        int wid  = blockIdx.x * 4 + (threadIdx.x >> 6);   // 0..6143
        int fm = wid & 255, kc = wid >> 8;
        int row = fm * 16 + (lane & 15);
        int col = kc * 32 + (lane >> 4) * 8;
        const float4* p = reinterpret_cast<const float4*>(&X[row * DM_ + col]);
        float4 x0 = p[0], x1 = p[1];
        float xs[8] = {x0.x, x0.y, x0.z, x0.w, x1.x, x1.y, x1.z, x1.w};
        f16x8 hi, lo;
        #pragma unroll
        for (int j = 0; j < 8; ++j) {
            float v = xs[j] * 256.0f;
            _Float16 h = (_Float16)v;
            hi[j] = h;
            lo[j] = (_Float16)(v - (float)h);
        }
        size_t out = ((size_t)wid * 64 + lane) * 8;
        *reinterpret_cast<f16x8*>(&Xh[out]) = hi;
        *reinterpret_cast<f16x8*>(&Xl[out]) = lo;
    } else {
        int wid  = (blockIdx.x - 1536) * 4 + (threadIdx.x >> 6);   // 0..3455
        int fn = wid % 48, kc = (wid / 48) % 24, which = wid / 1152;
        const float* __restrict__ W = which == 0 ? Wq : (which == 1 ? Wk : Wv);
        int c = lane & 15, g = lane >> 4;
        int ncol = fn * 16 + c;
        int krow = kc * 32 + g * 8;
        f16x8 hi, lo;
        #pragma unroll
        for (int j = 0; j < 8; ++j) {
            float v = W[(krow + j) * DM_ + ncol] * 256.0f;
            _Float16 h = (_Float16)v;
            hi[j] = h;
            lo[j] = (_Float16)(v - (float)h);
        }
        size_t out = ((size_t)wid * 64 + lane) * 8;
        *reinterpret_cast<f16x8*>(&Wth[out]) = hi;
        *reinterpret_cast<f16x8*>(&Wtl[out]) = lo;
    }
}

// ---------------- Kernel 1: QKV via fp16 split MFMA, LDS-staged dbuf -----------
// v14 = R16 main loop (known-good ~70us) + LDS-transposed PACKED Q/K stores:
// after the K-loop a __syncthreads retires fragment reads; each wave deposits
// its 32x48 fp32 tile into a wave-private 6KB LDS region, re-reads in
// store-major order, and emits f16x8 (16B) stores instead of 24-48 scalars.
// Values bitwise identical (same float -> same casts).
__global__ __launch_bounds__(512, 4) void qkv_mfma(
    const _Float16* __restrict__ Xh, const _Float16* __restrict__ Xl,
    const _Float16* __restrict__ Wth, const _Float16* __restrict__ Wtl,
    const float* __restrict__ X,
    const float* __restrict__ Wq, const float* __restrict__ bq,
    const float* __restrict__ Wk, const float* __restrict__ bk,
    const float* __restrict__ Wv, const float* __restrict__ bv,
    _Float16* __restrict__ Qf, _Float16* __restrict__ Kfh, _Float16* __restrict__ Kfl,
    _Float16* __restrict__ Vfh, _Float16* __restrict__ Vfl)
{
    // XCD epochs: per XCD 3 epochs x (4 mb x 8 nb) of one which.
    const int orig = blockIdx.x;
    const int xcd = orig & 7, idx = orig >> 3;        // idx 0..95
    const int epoch = idx >> 5, sub = idx & 31;       // 3 epochs x 32 blocks
    const int mw = xcd * 12 + epoch * 4 + (sub >> 3); // 0..95 bijective
    const int which = mw / 32, mb = mw % 32;
    const int nb = sub & 7;                           // 0..7 (96-col panels)

    const float* __restrict__ bias = which == 0 ? bq : (which == 1 ? bk : bv);

    // [buf][Ah 4096 | Al 4096 | Bh 3072 | Bl 3072] halves = 28KB/buf
    __shared__ __align__(16) _Float16 lds[2][14336];

    const int tid = threadIdx.x;
    const int wave = tid >> 6, lane = tid & 63;
    const int wm = wave >> 1, wn = wave & 1;          // wm 0..3, wn 0..1
    const int l15 = lane & 15, g = lane >> 4;

    auto stage = [&](int kc, int bsel) {
        #pragma unroll
        for (int c = 0; c < 4; ++c) {
            int u = wave * 4 + c;                     // 0..31; units 0..27 valid
            if (u < 28) {
                const _Float16* src;
                if (u < 8)       src = Xh  + (size_t)(kc * 256 + mb * 8 + u) * 512;
                else if (u < 16) src = Xl  + (size_t)(kc * 256 + mb * 8 + (u - 8)) * 512;
                else if (u < 22) src = Wth + (size_t)((which * 24 + kc) * 48 + nb * 6 + (u - 16)) * 512;
                else             src = Wtl + (size_t)((which * 24 + kc) * 48 + nb * 6 + (u - 22)) * 512;
                gload_lds16(src + lane * 8, &lds[bsel][u * 512]);
            }
        }
    };

    f32x4 acc[2][3];
    #pragma unroll
    for (int i = 0; i < 2; ++i)
        #pragma unroll
        for (int j = 0; j < 3; ++j) acc[i][j] = (f32x4){0.f, 0.f, 0.f, 0.f};

    stage(0, 0);
    __syncthreads();
    int cur = 0;

    for (int kc = 0; kc < 24; ++kc) {
        if (kc + 1 < 24) stage(kc + 1, cur ^ 1);     // prefetch flies under compute
        const _Float16* Bf = lds[cur];
        f16x8 ah[2], al[2], bh[3], bl[3];
        #pragma unroll
        for (int f = 0; f < 2; ++f) {
            ah[f] = *reinterpret_cast<const f16x8*>(&Bf[(wm * 2 + f) * 512 + lane * 8]);
            al[f] = *reinterpret_cast<const f16x8*>(&Bf[4096 + (wm * 2 + f) * 512 + lane * 8]);
        }
        #pragma unroll
        for (int fb = 0; fb < 3; ++fb) {
            bh[fb] = *reinterpret_cast<const f16x8*>(&Bf[8192 + (wn * 3 + fb) * 512 + lane * 8]);
            bl[fb] = *reinterpret_cast<const f16x8*>(&Bf[11264 + (wn * 3 + fb) * 512 + lane * 8]);
        }
        __builtin_amdgcn_s_setprio(1);
        #pragma unroll
        for (int i = 0; i < 2; ++i)
            #pragma unroll
            for (int j = 0; j < 3; ++j) {
                acc[i][j] = __builtin_amdgcn_mfma_f32_16x16x32_f16(ah[i], bh[j], acc[i][j], 0, 0, 0);
                acc[i][j] = __builtin_amdgcn_mfma_f32_16x16x32_f16(ah[i], bl[j], acc[i][j], 0, 0, 0);
                acc[i][j] = __builtin_amdgcn_mfma_f32_16x16x32_f16(al[i], bh[j], acc[i][j], 0, 0, 0);
            }
        __builtin_amdgcn_s_setprio(0);
        __syncthreads();                              // drains prefetch; buffers swap
        cur ^= 1;
    }

    const float* __restrict__ Worig = which == 0 ? Wq : (which == 1 ? Wk : Wv);

    __syncthreads();   // retire all fragment reads before reusing lds as ldsF
    float* __restrict__ ldsF = reinterpret_cast<float*>(&lds[0][0]) + wave * 1536;  // 6KB/wave

    #pragma unroll
    for (int i = 0; i < 2; ++i) {
        #pragma unroll
        for (int j = 0; j < 3; ++j) {
            int n = nb * 96 + wn * 48 + j * 16 + l15;
            int h = n >> 6, d = n & 63;
            float bn = bias[n];
            float vals[4];
            #pragma unroll
            for (int r = 0; r < 4; ++r) {
                float val = acc[i][j][r] * (1.0f / 65536.0f) + bn;
                if (which < 2) {
                    bool need = fabsf(fabsf(val) - 1.0f) < 1e-4f;
                    unsigned long long msk = __ballot(need);
                    // wave-parallel deterministic recompute per flagged lane
                    while (msk) {
                        int L = (int)__builtin_ctzll(msk);
                        msk &= msk - 1;
                        int Lm = mb * 128 + wm * 32 + i * 16 + (L >> 4) * 4 + r;
                        int Ln = nb * 96 + wn * 48 + j * 16 + (L & 15);
                        const float* xr = X + (size_t)Lm * DM_;
                        const float* wc = Worig + Ln;
                        float xs[12], wsv[12];
                        #pragma unroll
                        for (int t = 0; t < 12; ++t) {
                            int e = t * 64 + lane;
                            xs[t]  = xr[e];
                            wsv[t] = wc[(size_t)e * DM_];
                        }
                        float part = 0.0f;
                        #pragma unroll
                        for (int t = 0; t < 12; ++t) part = fmaf(xs[t], wsv[t], part);
                        part += __shfl_xor(part, 1);
                        part += __shfl_xor(part, 2);
                        part += __shfl_xor(part, 4);
                        part += __shfl_xor(part, 8);
                        part += __shfl_xor(part, 16);
                        part += __shfl_xor(part, 32);
                        if (lane == L) val = part + bn;
                    }
                }
                vals[r] = val;
            }
            if (which == 0) {
                // deposit spike(val) to wave-private LDS tile [ls 32][ld 48]
                #pragma unroll
                for (int r = 0; r < 4; ++r)
                    ldsF[(i * 16 + g * 4 + r) * 48 + j * 16 + l15] = dual_spike(vals[r]);
            } else if (which == 1) {
                // deposit scaled hybrid value (float exact)
                #pragma unroll
                for (int r = 0; r < 4; ++r) {
                    float kv = 0.5f * dual_spike(vals[r]) + 0.5f * vals[r];
                    ldsF[(i * 16 + g * 4 + r) * 48 + j * 16 + l15] = kv * 256.0f;
                }
            } else {
                // V: already-packed f16x4 stores (r=0..3 consecutive k&7 slots)
                int m0 = mb * 128 + wm * 32 + i * 16 + g * 4;
                int b = m0 >> 9, s0 = m0 & 511;
                int bh_ = b * H_ + h;
                f16x4 ph4, pl4;
                #pragma unroll
                for (int r = 0; r < 4; ++r) {
                    _Float16 hh = (_Float16)vals[r];
                    ph4[r] = hh;
                    pl4[r] = (_Float16)(vals[r] - (float)hh);
                }
                size_t unit = (size_t)(bh_ * 16 + (s0 >> 5)) * 4 + (d >> 4);
                size_t off = unit * 512 + (size_t)(((s0 >> 3) & 3) * 16 + (d & 15)) * 8 + (s0 & 7);
                *reinterpret_cast<f16x4*>(&Vfh[off]) = ph4;
                *reinterpret_cast<f16x4*>(&Vfl[off]) = pl4;
            }
        }
    }

    if (which < 2) {
        asm volatile("s_waitcnt lgkmcnt(0)" ::: "memory");   // wave's ldsF writes done
        __builtin_amdgcn_sched_barrier(0);
        #pragma unroll
        for (int t = 0; t < 3; ++t) {
            int run = t * 64 + lane;            // 0..191 = 32 ls x 6 d8-runs
            int ls = run / 6, ld0 = (run % 6) * 8;
            float v8[8];
            #pragma unroll
            for (int e = 0; e < 8; ++e) v8[e] = ldsF[ls * 48 + ld0 + e];
            int s = mb * 128 + wm * 32 + ls;
            int n = nb * 96 + wn * 48 + ld0;    // multiple of 8; run stays in one h
            int h = n >> 6, d0 = n & 63;
            int b = s >> 9, sl = s & 511;
            int bh_ = b * H_ + h;
            size_t unit = (size_t)(bh_ * 32 + (sl >> 4)) * 2 + (d0 >> 5);
            size_t off = unit * 512 + (size_t)(((d0 >> 3) & 3) * 16 + (sl & 15)) * 8;  // d&7 = 0
            if (which == 0) {
                f16x8 o;
                #pragma unroll
                for (int e = 0; e < 8; ++e) o[e] = (_Float16)v8[e];
                *reinterpret_cast<f16x8*>(&Qf[off]) = o;
            } else {
                f16x8 oh, ol;
                #pragma unroll
                for (int e = 0; e < 8; ++e) {
                    _Float16 hh = (_Float16)v8[e];
                    oh[e] = hh;
                    ol[e] = (_Float16)(v8[e] - (float)hh);
                }
                *reinterpret_cast<f16x8*>(&Kfh[off]) = oh;
                *reinterpret_cast<f16x8*>(&Kfl[off]) = ol;
            }
        }
    }
}

// ---------------- Kernel 2: score threshold counts via MFMA --------------------
__global__ __launch_bounds__(256) void score_sums(
    const _Float16* __restrict__ Qf, const _Float16* __restrict__ Kfh,
    const _Float16* __restrict__ Kfl,
    float* __restrict__ xh, float* __restrict__ xw)
{
    const int orig = blockIdx.x;
    const int xcd = orig & 7, idx = orig >> 3;
    const int bh = xcd * 12 + idx / 8, qt = idx & 7;
    const int tid = threadIdx.x, wave = tid >> 6, lane = tid & 63;
    const int l15 = lane & 15, g = lane >> 4;

    __shared__ float rowred[4][64];

    f16x8 qa[4][2];
    #pragma unroll
    for (int sf = 0; sf < 4; ++sf) {
        const _Float16* qb = Qf + (size_t)((bh * 32 + qt * 4 + sf) * 2) * 512 + lane * 8;
        qa[sf][0] = *reinterpret_cast<const f16x8*>(qb);
        qa[sf][1] = *reinterpret_cast<const f16x8*>(qb + 512);
    }
    float rowc[4][4];
    #pragma unroll
    for (int sf = 0; sf < 4; ++sf)
        #pragma unroll
        for (int r = 0; r < 4; ++r) rowc[sf][r] = 0.0f;

    for (int sc8 = 0; sc8 < 8; ++sc8) {
        int scol16 = sc8 * 4 + wave;
        const _Float16* kbh = Kfh + (size_t)((bh * 32 + scol16) * 2) * 512 + lane * 8;
        const _Float16* kbl = Kfl + (size_t)((bh * 32 + scol16) * 2) * 512 + lane * 8;
        f16x8 kh[2] = {*reinterpret_cast<const f16x8*>(kbh),
                       *reinterpret_cast<const f16x8*>(kbh + 512)};
        f16x8 kl[2] = {*reinterpret_cast<const f16x8*>(kbl),
                       *reinterpret_cast<const f16x8*>(kbl + 512)};
        float csum = 0.0f;
        #pragma unroll
        for (int sf = 0; sf < 4; ++sf) {
            f32x4 acc = qk_dot(qa[sf], kh, kl);
            #pragma unroll
            for (int r = 0; r < 4; ++r) {
                float t1 = acc[r] >= 2048.0f ? 1.0f : 0.0f;   // dot >= 8
                rowc[sf][r] += t1;
                csum += t1;
            }
        }
        csum += __shfl_xor(csum, 16);
        csum += __shfl_xor(csum, 32);
        if (g == 0) atomicAdd(&xw[bh * S_ + scol16 * 16 + l15], csum);
    }
    #pragma unroll
    for (int sf = 0; sf < 4; ++sf)
        #pragma unroll
        for (int r = 0; r < 4; ++r) {
            float sv = rowc[sf][r];
            sv += __shfl_xor(sv, 1); sv += __shfl_xor(sv, 2);
            sv += __shfl_xor(sv, 4); sv += __shfl_xor(sv, 8);
            if (l15 == 0) rowred[wave][sf * 16 + g * 4 + r] = sv;
        }
    __syncthreads();
    if (tid < 64) {
        float sv = rowred[0][tid] + rowred[1][tid] + rowred[2][tid] + rowred[3][tid];
        xh[bh * S_ + qt * 64 + tid] = sv;    // exact count, no atomics needed
    }
}

// ---------------- Kernel 3a: conv1 y + per-block partial stats (deterministic) --
__global__ __launch_bounds__(256) void small_a(
    const float* __restrict__ xh, const float* __restrict__ xw,
    const float* __restrict__ c1w,
    float* __restrict__ y, float* __restrict__ stats_part)   // [24][2]
{
    const int tid = threadIdx.x;
    const int br = blockIdx.x;           // b*3 + r
    const int r = br % 3, b = br / 3;
    __shared__ float c1s[12];
    __shared__ float red[256], red2[256];
    if (tid < 12) c1s[tid] = c1w[r * 12 + tid];
    __syncthreads();

    float psum = 0.0f, psq = 0.0f;
    for (int n = tid; n < 1024; n += 256) {
        float acc = 0.0f;
        #pragma unroll
        for (int h = 0; h < 12; ++h) {
            float cv = (n < 512) ? xh[(b * H_ + h) * S_ + n]
                                 : xw[(b * H_ + h) * S_ + (n - 512)];
            acc = fmaf(c1s[h], cv * (1.0f / 512.0f), acc);
        }
        y[br * 1024 + n] = acc;
        psum += acc;
        psq = fmaf(acc, acc, psq);
    }
    red[tid] = psum; red2[tid] = psq;
    __syncthreads();
    for (int o = 128; o > 0; o >>= 1) {
        if (tid < o) { red[tid] += red[tid + o]; red2[tid] += red2[tid + o]; }
        __syncthreads();
    }
    if (tid == 0) {
        stats_part[br * 2 + 0] = red[0];
        stats_part[br * 2 + 1] = red2[0];
    }
}

// ---------------- Kernel 3b: BN + relu + conv + sigmoid ------------------------
__global__ __launch_bounds__(512) void small_b(
    const float* __restrict__ y, const float* __restrict__ stats_part,
    const float* __restrict__ gamma, const float* __restrict__ beta,
    const float* __restrict__ chw, const float* __restrict__ cww,
    float* __restrict__ s_h, float* __restrict__ s_w)
{
    int e = blockIdx.x * 512 + threadIdx.x;   // 0..49151
    int s = e & 511; int bh = e >> 9; int h = bh % H_; int b = bh / H_;
    float ah = 0.0f, aw = 0.0f;
    #pragma unroll
    for (int r = 0; r < 3; ++r) {
        float su = 0.0f, sq = 0.0f;
        #pragma unroll
        for (int bb = 0; bb < 8; ++bb) {     // fixed order -> deterministic
            su += stats_part[(bb * 3 + r) * 2 + 0];
            sq += stats_part[(bb * 3 + r) * 2 + 1];
        }
        float mu = su * (1.0f / 8192.0f);
        float var = sq * (1.0f / 8192.0f) - mu * mu;
        float rs = rsqrtf(var + 1e-5f);
        int yb = (b * 3 + r) << 10;
        float yh = fmaxf((y[yb + s]       - mu) * rs * gamma[r] + beta[r], 0.0f);
        float yw = fmaxf((y[yb + 512 + s] - mu) * rs * gamma[r] + beta[r], 0.0f);
        ah = fmaf(chw[h * 3 + r], yh, ah);
        aw = fmaf(cww[h * 3 + r], yw, aw);
    }
    s_h[e] = 1.0f / (1.0f + expf(-ah));
    s_w[e] = 1.0f / (1.0f + expf(-aw));
}

// ---------------- Kernel 4: full-MFMA attention (R13/R14, unchanged) ------------
__global__ __launch_bounds__(256) void attn_pv(
    const _Float16* __restrict__ Qf, const _Float16* __restrict__ Kfh,
    const _Float16* __restrict__ Kfl,
    const _Float16* __restrict__ Vfh, const _Float16* __restrict__ Vfl,
    const float* __restrict__ mask, const float* __restrict__ s_h,
    const float* __restrict__ s_w, float* __restrict__ out)
{
    __shared__ __align__(16) _Float16 Kst[2][4096];
    __shared__ __align__(16) _Float16 Vst[2][4096];
    __shared__ __align__(16) float P_lds[64][68];

    const int orig = blockIdx.x;
    const int xcd = orig & 7, idx = orig >> 3;
    const int bh = xcd * 12 + idx / 8, qt = idx & 7;
    const int b = bh / H_, h = bh % H_;
    const int q0 = qt * 64;
    const int tid = threadIdx.x, wave = tid >> 6, lane = tid & 63;
    const int l15 = lane & 15, g = lane >> 4;
    const int rl = wave * 16 + g * 4;

    const _Float16* qb = Qf + (size_t)((bh * 32 + qt * 4 + wave) * 2) * 512 + lane * 8;
    f16x8 qa[2] = {*reinterpret_cast<const f16x8*>(qb),
                   *reinterpret_cast<const f16x8*>(qb + 512)};

    float shq[4];
    #pragma unroll
    for (int r = 0; r < 4; ++r) shq[r] = s_h[bh * S_ + q0 + rl + r];

    auto stageK = [&](int kt) {
        const _Float16* sh_ = Kfh + (size_t)((bh * 32 + kt * 4) * 2) * 512;
        const _Float16* sl_ = Kfl + (size_t)((bh * 32 + kt * 4) * 2) * 512;
        #pragma unroll
        for (int c = 0; c < 2; ++c) {
            int u = (c * 4 + wave) * 512;
            gload_lds16(&sh_[u + lane * 8], &Kst[0][u]);
            gload_lds16(&sl_[u + lane * 8], &Kst[1][u]);
        }
    };
    auto stageV = [&](int kt) {
        const _Float16* vh_ = Vfh + (size_t)((bh * 16 + kt * 2) * 4) * 512;
        const _Float16* vl_ = Vfl + (size_t)((bh * 16 + kt * 2) * 4) * 512;
        #pragma unroll
        for (int c = 0; c < 2; ++c) {
            int u = (c * 4 + wave) * 512;
            gload_lds16(&vh_[u + lane * 8], &Vst[0][u]);
            gload_lds16(&vl_[u + lane * 8], &Vst[1][u]);
        }
    };

    float m_r[4], l_r[4];
    f32x4 ctx[4];
    #pragma unroll
    for (int r = 0; r < 4; ++r) m_r[r] = -INFINITY, l_r[r] = 0.0f;
    #pragma unroll
    for (int fd = 0; fd < 4; ++fd) ctx[fd] = (f32x4){0.f, 0.f, 0.f, 0.f};

    stageK(0); stageV(0);
    __syncthreads();

    for (int kt = 0; kt < 8; ++kt) {
        float sc[4][4];
        __builtin_amdgcn_s_setprio(1);
        #pragma unroll
        for (int fc = 0; fc < 4; ++fc) {
            f16x8 kh[2] = {*reinterpret_cast<const f16x8*>(&Kst[0][(fc * 2 + 0) * 512 + lane * 8]),
                           *reinterpret_cast<const f16x8*>(&Kst[0][(fc * 2 + 1) * 512 + lane * 8])};
            f16x8 kl[2] = {*reinterpret_cast<const f16x8*>(&Kst[1][(fc * 2 + 0) * 512 + lane * 8]),
                           *reinterpret_cast<const f16x8*>(&Kst[1][(fc * 2 + 1) * 512 + lane * 8])};
            f32x4 acc = qk_dot(qa, kh, kl);
            int col = kt * 64 + fc * 16 + l15;
            float mj  = mask[b * S_ + col];
            float swj = s_w[bh * S_ + col];
            #pragma unroll
            for (int r = 0; r < 4; ++r) {
                float t1 = acc[r] >= 2048.0f ? 1.0f : 0.0f;
                sc[fc][r] = acc[r] * 4.8828125e-4f + mj + t1 * (shq[r] * swj);
            }
        }
        __builtin_amdgcn_s_setprio(0);
        __syncthreads();
        if (kt < 7) stageK(kt + 1);

        float p[4][4], cscale[4];
        #pragma unroll
        for (int r = 0; r < 4; ++r) {
            float tmax = fmaxf(fmaxf(sc[0][r], sc[1][r]), fmaxf(sc[2][r], sc[3][r]));
            tmax = fmaxf(tmax, __shfl_xor(tmax, 1));
            tmax = fmaxf(tmax, __shfl_xor(tmax, 2));
            tmax = fmaxf(tmax, __shfl_xor(tmax, 4));
            tmax = fmaxf(tmax, __shfl_xor(tmax, 8));
            float mn = fmaxf(m_r[r], tmax);
            float ps = 0.0f;
            #pragma unroll
            for (int fc = 0; fc < 4; ++fc) { p[fc][r] = expf(sc[fc][r] - mn); ps += p[fc][r]; }
            ps += __shfl_xor(ps, 1); ps += __shfl_xor(ps, 2);
            ps += __shfl_xor(ps, 4); ps += __shfl_xor(ps, 8);
            float scale = expf(m_r[r] - mn);
            l_r[r] = l_r[r] * scale + ps;
            m_r[r] = mn;
            cscale[r] = scale;
        }
        #pragma unroll
        for (int fc = 0; fc < 4; ++fc)
            #pragma unroll
            for (int r = 0; r < 4; ++r)
                P_lds[rl + r][fc * 16 + l15] = p[fc][r];

        f16x8 ph[2], pl[2];
        #pragma unroll
        for (int c = 0; c < 2; ++c) {
            f32x4 pa = *reinterpret_cast<const f32x4*>(&P_lds[wave * 16 + l15][c * 32 + g * 8]);
            f32x4 pb = *reinterpret_cast<const f32x4*>(&P_lds[wave * 16 + l15][c * 32 + g * 8 + 4]);
            float pv8[8] = {pa[0], pa[1], pa[2], pa[3], pb[0], pb[1], pb[2], pb[3]};
            #pragma unroll
            for (int j = 0; j < 8; ++j) {
                _Float16 hh = (_Float16)pv8[j];
                ph[c][j] = hh;
                pl[c][j] = (_Float16)(pv8[j] - (float)hh);
            }
        }
        #pragma unroll
        for (int fd = 0; fd < 4; ++fd)
            #pragma unroll
            for (int r = 0; r < 4; ++r) ctx[fd][r] *= cscale[r];

        __builtin_amdgcn_s_setprio(1);
        #pragma unroll
        for (int fd = 0; fd < 4; ++fd) {
            f16x8 vh0 = *reinterpret_cast<const f16x8*>(&Vst[0][(0 * 4 + fd) * 512 + lane * 8]);
            f16x8 vl0 = *reinterpret_cast<const f16x8*>(&Vst[1][(0 * 4 + fd) * 512 + lane * 8]);
            f16x8 vh1 = *reinterpret_cast<const f16x8*>(&Vst[0][(1 * 4 + fd) * 512 + lane * 8]);
            f16x8 vl1 = *reinterpret_cast<const f16x8*>(&Vst[1][(1 * 4 + fd) * 512 + lane * 8]);
            ctx[fd] = __builtin_amdgcn_mfma_f32_16x16x32_f16(ph[0], vh0, ctx[fd], 0, 0, 0);
            ctx[fd] = __builtin_amdgcn_mfma_f32_16x16x32_f16(ph[0], vl0, ctx[fd], 0, 0, 0);
            ctx[fd] = __builtin_amdgcn_mfma_f32_16x16x32_f16(pl[0], vh0, ctx[fd], 0, 0, 0);
            ctx[fd] = __builtin_amdgcn_mfma_f32_16x16x32_f16(ph[1], vh1, ctx[fd], 0, 0, 0);
            ctx[fd] = __builtin_amdgcn_mfma_f32_16x16x32_f16(ph[1], vl1, ctx[fd], 0, 0, 0);
            ctx[fd] = __builtin_amdgcn_mfma_f32_16x16x32_f16(pl[1], vh1, ctx[fd], 0, 0, 0);
        }
        __builtin_amdgcn_s_setprio(0);
        __syncthreads();
        if (kt < 7) stageV(kt + 1);
    }
    #pragma unroll
    for (int r = 0; r < 4; ++r) {
        int s = q0 + rl + r;
        float inv = 1.0f / l_r[r];
        float* orow = &out[((size_t)b * S_ + s) * DM_ + h * D_];
        #pragma unroll
        for (int fd = 0; fd < 4; ++fd)
            orow[fd * 16 + l15] = ctx[fd][r] * inv;
    }
}

extern "C" void kernel_launch(void* const* d_in, const int* in_sizes, int n_in,
                              void* d_out, int out_size, void* d_ws, size_t ws_size,
                              hipStream_t stream) {
    const float* X    = (const float*)d_in[0];
    const float* mask = (const float*)d_in[1];
    const float* Wq   = (const float*)d_in[2];
    const float* bq   = (const float*)d_in[3];
    const float* Wk   = (const float*)d_in[4];
    const float* bk   = (const float*)d_in[5];
    const float* Wv   = (const float*)d_in[6];
    const float* bv   = (const float*)d_in[7];
    const float* c1w  = (const float*)d_in[8];
    const float* gam  = (const float*)d_in[9];
    const float* bet  = (const float*)d_in[10];
    const float* chw  = (const float*)d_in[11];
    const float* cww  = (const float*)d_in[12];
    float* out = (float*)d_out;

    float* ws = (float*)d_ws;
    // Fragments live in the former q/k/v fp32 regions (no fp32 round-trip):
    _Float16* Qf  = (_Float16*)ws;                 // 6.3 MB (q region, 12.6 MB)
    float* stats_part = (float*)(Qf + 3145728);    // 48 floats, q region spare
    _Float16* Kfh = (_Float16*)(ws + 3145728);     // k region
    _Float16* Kfl = Kfh + 3145728;
    _Float16* Vfh = (_Float16*)(ws + 2 * 3145728); // v region
    _Float16* Vfl = Vfh + 3145728;
    float* xh = ws + 3 * 3145728;                  // 49152
    float* xw = xh + 49152;
    float* y  = xw + 49152;                        // 24576
    float* sh = y  + 24576;
    float* sw = sh + 49152;
    _Float16* Xh  = (_Float16*)(sw + 49152);       // 3145728 halves (staging)
    _Float16* Xl  = Xh + 3145728;
    _Float16* Wth = Xl + 3145728;                  // 1769472 halves
    _Float16* Wtl = Wth + 1769472;                 // total ws ~55.6 MiB

    hipMemsetAsync(xw, 0, 49152 * sizeof(float), stream);

    prep_xw<<<2400, 256, 0, stream>>>(X, Wq, Wk, Wv, Xh, Xl, Wth, Wtl);
    qkv_mfma<<<768, 512, 0, stream>>>(Xh, Xl, Wth, Wtl,
        X, Wq, bq, Wk, bk, Wv, bv, Qf, Kfh, Kfl, Vfh, Vfl);
    score_sums<<<768, 256, 0, stream>>>(Qf, Kfh, Kfl, xh, xw);
    small_a<<<24, 256, 0, stream>>>(xh, xw, c1w, y, stats_part);
    small_b<<<96, 512, 0, stream>>>(y, stats_part, gam, bet, chw, cww, sh, sw);
    attn_pv<<<768, 256, 0, stream>>>(Qf, Kfh, Kfl, Vfh, Vfl, mask, sh, sw, out);
}